// Round 1
// baseline (1853.799 us; speedup 1.0000x reference)
//
#include <hip/hip_runtime.h>

#define N_VNS   8192
#define N_CNS   4096
#define BATCH   1024
#define B4      (BATCH/4)
#define NUM_ITER 20
#define PHI_MIN 8.5e-08f
#define PHI_MAX 16.635532f

__device__ __forceinline__ float phi_f(float x) {
    x = fminf(fmaxf(x, PHI_MIN), PHI_MAX);
    float e = expf(x);
    return logf(e + 1.0f) - logf(e - 1.0f);
}

// ---------- setup kernels (run once per launch) ----------

__global__ void transpose_neg(const float* __restrict__ in, float* __restrict__ out,
                              int rows, int cols) {
    // out[c][r] = -in[r][c]
    __shared__ float tile[32][33];
    int bx = blockIdx.x * 32;   // col base
    int by = blockIdx.y * 32;   // row base
    int tx = threadIdx.x, ty = threadIdx.y;   // 32 x 8
    #pragma unroll
    for (int i = 0; i < 32; i += 8)
        tile[ty + i][tx] = in[(size_t)(by + ty + i) * cols + bx + tx];
    __syncthreads();
    #pragma unroll
    for (int i = 0; i < 32; i += 8)
        out[(size_t)(bx + ty + i) * rows + by + tx] = -tile[tx][ty + i];
}

__global__ void count_edges(const int* __restrict__ vn_con, const int* __restrict__ cn_con,
                            int E, int* __restrict__ vn_cnt, int* __restrict__ cn_cnt) {
    int e = blockIdx.x * 256 + threadIdx.x;
    if (e < E) {
        atomicAdd(&vn_cnt[vn_con[e]], 1);
        atomicAdd(&cn_cnt[cn_con[e]], 1);
    }
}

__global__ void scan_excl(const int* __restrict__ cnt, int n, int* __restrict__ ptr) {
    __shared__ int sh[1024];
    int carry = 0;
    if (threadIdx.x == 0) ptr[0] = 0;
    for (int base = 0; base < n; base += 1024) {
        int i = base + (int)threadIdx.x;
        int v = (i < n) ? cnt[i] : 0;
        sh[threadIdx.x] = v;
        __syncthreads();
        for (int off = 1; off < 1024; off <<= 1) {
            int add = ((int)threadIdx.x >= off) ? sh[threadIdx.x - off] : 0;
            __syncthreads();
            sh[threadIdx.x] += add;
            __syncthreads();
        }
        if (i < n) ptr[i + 1] = carry + sh[threadIdx.x];
        carry += sh[1023];
        __syncthreads();
    }
}

__global__ void fill_vn(const int* __restrict__ vn_con, int E,
                        const int* __restrict__ vn_ptr, int* __restrict__ vn_fill,
                        int* __restrict__ vn_eids) {
    int e = blockIdx.x * 256 + threadIdx.x;
    if (e < E) {
        int v = vn_con[e];
        int slot = atomicAdd(&vn_fill[v], 1);
        vn_eids[vn_ptr[v] + slot] = e;
    }
}

// deterministic CSR: sort each vn's (<=3) edge ids ascending
__global__ void sort_vn(const int* __restrict__ vn_ptr, int* __restrict__ vn_eids) {
    int v = blockIdx.x * 256 + threadIdx.x;
    if (v >= N_VNS) return;
    int s = vn_ptr[v], n = vn_ptr[v + 1] - s;
    for (int i = 1; i < n; ++i) {
        int key = vn_eids[s + i];
        int j = i - 1;
        while (j >= 0 && vn_eids[s + j] > key) { vn_eids[s + j + 1] = vn_eids[s + j]; --j; }
        vn_eids[s + j + 1] = key;
    }
}

// ---------- per-iteration kernels ----------

// node_sum[v][:] = llrT[v][:] + sum_{e in edges(v)} msg[e][:]
__global__ __launch_bounds__(256) void vn_sum(const float4* __restrict__ llrT,
                                              const float4* __restrict__ msg,
                                              const int* __restrict__ vn_ptr,
                                              const int* __restrict__ vn_eids,
                                              float4* __restrict__ node_sum) {
    int v = blockIdx.x;
    int tid = threadIdx.x;
    float4 acc = llrT[(size_t)v * B4 + tid];
    int s = vn_ptr[v], e = vn_ptr[v + 1];
    #pragma unroll
    for (int k = 0; k < 3; ++k) {
        if (s + k < e) {
            int eid = vn_eids[s + k];
            float4 m = msg[(size_t)eid * B4 + tid];
            acc.x += m.x; acc.y += m.y; acc.z += m.z; acc.w += m.w;
        }
    }
    node_sum[(size_t)v * B4 + tid] = acc;
}

// in-place CN update: t = node_sum[vn_e] - msg[e];  msg[e] = sign_out * phi(psum - p_e)
__global__ __launch_bounds__(256) void cn_update(const float4* __restrict__ node_sum,
                                                 float4* __restrict__ msg,
                                                 const int* __restrict__ cn_ptr,
                                                 const int* __restrict__ vn_con) {
    int j = blockIdx.x;
    int tid = threadIdx.x;
    int s = cn_ptr[j], e = cn_ptr[j + 1];
    int deg = e - s;

    float4 p[6];
    uint4 m = make_uint4(0u, 0u, 0u, 0u);
    float4 psum = make_float4(0.f, 0.f, 0.f, 0.f);

    #pragma unroll
    for (int k = 0; k < 6; ++k) {
        if (k < deg) {
            int eid = s + k;
            int v = vn_con[eid];
            float4 ns = node_sum[(size_t)v * B4 + tid];
            float4 mm = msg[(size_t)eid * B4 + tid];
            float tx = ns.x - mm.x, ty = ns.y - mm.y, tz = ns.z - mm.z, tw = ns.w - mm.w;
            if (tx < 0.f) m.x |= (1u << k);
            if (ty < 0.f) m.y |= (1u << k);
            if (tz < 0.f) m.z |= (1u << k);
            if (tw < 0.f) m.w |= (1u << k);
            float px = phi_f(fabsf(tx));
            float py = phi_f(fabsf(ty));
            float pz = phi_f(fabsf(tz));
            float pw = phi_f(fabsf(tw));
            p[k] = make_float4(px, py, pz, pw);
            psum.x += px; psum.y += py; psum.z += pz; psum.w += pw;
        }
    }

    float ax = (__popc(m.x) & 1) ? -1.f : 1.f;
    float ay = (__popc(m.y) & 1) ? -1.f : 1.f;
    float az = (__popc(m.z) & 1) ? -1.f : 1.f;
    float aw = (__popc(m.w) & 1) ? -1.f : 1.f;

    #pragma unroll
    for (int k = 0; k < 6; ++k) {
        if (k < deg) {
            int eid = s + k;
            float4 o;
            o.x = (((m.x >> k) & 1) ? -ax : ax) * phi_f(psum.x - p[k].x);
            o.y = (((m.y >> k) & 1) ? -ay : ay) * phi_f(psum.y - p[k].y);
            o.z = (((m.z >> k) & 1) ? -az : az) * phi_f(psum.z - p[k].z);
            o.w = (((m.w >> k) & 1) ? -aw : aw) * phi_f(psum.w - p[k].w);
            msg[(size_t)eid * B4 + tid] = o;
        }
    }
}

extern "C" void kernel_launch(void* const* d_in, const int* in_sizes, int n_in,
                              void* d_out, int out_size, void* d_ws, size_t ws_size,
                              hipStream_t stream) {
    const float* llr_ch = (const float*)d_in[0];
    const int* vn_con = (const int*)d_in[1];
    const int* cn_con = (const int*)d_in[2];
    int E = in_sizes[1];
    float* out = (float*)d_out;

    char* ws = (char*)d_ws;
    size_t off = 0;
    auto alloc = [&](size_t bytes) -> void* {
        void* ptr = ws + off;
        off = (off + bytes + 255) & ~(size_t)255;
        return ptr;
    };
    float* llrT     = (float*)alloc((size_t)N_VNS * BATCH * 4);
    float* node_sum = (float*)alloc((size_t)N_VNS * BATCH * 4);
    float* msg      = (float*)alloc((size_t)E * BATCH * 4);
    int* vn_ptr  = (int*)alloc((N_VNS + 1) * 4);
    int* cn_ptr  = (int*)alloc((N_CNS + 1) * 4);
    int* vn_cnt  = (int*)alloc(N_VNS * 4);
    int* cn_cnt  = (int*)alloc(N_CNS * 4);
    int* vn_fill = (int*)alloc(N_VNS * 4);
    int* vn_eids = (int*)alloc((size_t)E * 4);

    hipMemsetAsync(vn_cnt, 0, N_VNS * 4, stream);
    hipMemsetAsync(cn_cnt, 0, N_CNS * 4, stream);
    hipMemsetAsync(vn_fill, 0, N_VNS * 4, stream);
    hipMemsetAsync(msg, 0, (size_t)E * BATCH * 4, stream);

    // llrT[v][b] = -llr_ch[b][v]
    transpose_neg<<<dim3(N_VNS / 32, BATCH / 32), dim3(32, 8), 0, stream>>>(
        llr_ch, llrT, BATCH, N_VNS);

    count_edges<<<(E + 255) / 256, 256, 0, stream>>>(vn_con, cn_con, E, vn_cnt, cn_cnt);
    scan_excl<<<1, 1024, 0, stream>>>(vn_cnt, N_VNS, vn_ptr);
    scan_excl<<<1, 1024, 0, stream>>>(cn_cnt, N_CNS, cn_ptr);
    fill_vn<<<(E + 255) / 256, 256, 0, stream>>>(vn_con, E, vn_ptr, vn_fill, vn_eids);
    sort_vn<<<(N_VNS + 255) / 256, 256, 0, stream>>>(vn_ptr, vn_eids);

    for (int it = 0; it < NUM_ITER; ++it) {
        vn_sum<<<N_VNS, 256, 0, stream>>>((const float4*)llrT, (const float4*)msg,
                                          vn_ptr, vn_eids, (float4*)node_sum);
        cn_update<<<N_CNS, 256, 0, stream>>>((const float4*)node_sum, (float4*)msg,
                                             cn_ptr, vn_con);
    }

    // x_tot = llrT + segment_sum(msg); out[b][v] = -x_tot[v][b]
    vn_sum<<<N_VNS, 256, 0, stream>>>((const float4*)llrT, (const float4*)msg,
                                      vn_ptr, vn_eids, (float4*)node_sum);
    transpose_neg<<<dim3(BATCH / 32, N_VNS / 32), dim3(32, 8), 0, stream>>>(
        node_sum, out, N_VNS, BATCH);
}

// Round 2
// 1495.735 us; speedup vs baseline: 1.2394x; 1.2394x over previous
//
#include <hip/hip_runtime.h>

#define N_VNS   8192
#define N_CNS   4096
#define BATCH   1024
#define B4      (BATCH/4)
#define NUM_ITER 20
#define PHI_MIN 8.5e-08f
#define PHI_MAX 16.635532f

// phi(x) = log((e^x+1)/(e^x-1)) via hardware exp2/log2/rcp.
// e-1 clamped to 2^-23 (1 ulp at 1.0) to mimic the reference's f32 rounding
// at the PHI_MIN boundary and avoid rcp(0)=inf.
__device__ __forceinline__ float phi_f(float x) {
    x = fminf(fmaxf(x, PHI_MIN), PHI_MAX);
    float e = __builtin_amdgcn_exp2f(x * 1.44269504088896f);
    float em1 = fmaxf(e - 1.0f, 1.1920929e-07f);
    float r = (e + 1.0f) * __builtin_amdgcn_rcpf(em1);
    return __builtin_amdgcn_logf(r) * 0.693147180559945f;
}

// ---------- setup kernels (run once per launch) ----------

__global__ void transpose_neg(const float* __restrict__ in, float* __restrict__ out,
                              int rows, int cols) {
    // out[c][r] = -in[r][c]
    __shared__ float tile[32][33];
    int bx = blockIdx.x * 32;   // col base
    int by = blockIdx.y * 32;   // row base
    int tx = threadIdx.x, ty = threadIdx.y;   // 32 x 8
    #pragma unroll
    for (int i = 0; i < 32; i += 8)
        tile[ty + i][tx] = in[(size_t)(by + ty + i) * cols + bx + tx];
    __syncthreads();
    #pragma unroll
    for (int i = 0; i < 32; i += 8)
        out[(size_t)(bx + ty + i) * rows + by + tx] = -tile[tx][ty + i];
}

__global__ void count_edges(const int* __restrict__ vn_con, const int* __restrict__ cn_con,
                            int E, int* __restrict__ vn_cnt, int* __restrict__ cn_cnt) {
    int e = blockIdx.x * 256 + threadIdx.x;
    if (e < E) {
        atomicAdd(&vn_cnt[vn_con[e]], 1);
        atomicAdd(&cn_cnt[cn_con[e]], 1);
    }
}

__global__ void scan_excl(const int* __restrict__ cnt, int n, int* __restrict__ ptr) {
    __shared__ int sh[1024];
    int carry = 0;
    if (threadIdx.x == 0) ptr[0] = 0;
    for (int base = 0; base < n; base += 1024) {
        int i = base + (int)threadIdx.x;
        int v = (i < n) ? cnt[i] : 0;
        sh[threadIdx.x] = v;
        __syncthreads();
        for (int off = 1; off < 1024; off <<= 1) {
            int add = ((int)threadIdx.x >= off) ? sh[threadIdx.x - off] : 0;
            __syncthreads();
            sh[threadIdx.x] += add;
            __syncthreads();
        }
        if (i < n) ptr[i + 1] = carry + sh[threadIdx.x];
        carry += sh[1023];
        __syncthreads();
    }
}

__global__ void fill_vn(const int* __restrict__ vn_con, int E,
                        const int* __restrict__ vn_ptr, int* __restrict__ vn_fill,
                        int* __restrict__ vn_eids) {
    int e = blockIdx.x * 256 + threadIdx.x;
    if (e < E) {
        int v = vn_con[e];
        int slot = atomicAdd(&vn_fill[v], 1);
        vn_eids[vn_ptr[v] + slot] = e;
    }
}

// deterministic CSR: sort each vn's (<=3) edge ids ascending
__global__ void sort_vn(const int* __restrict__ vn_ptr, int* __restrict__ vn_eids) {
    int v = blockIdx.x * 256 + threadIdx.x;
    if (v >= N_VNS) return;
    int s = vn_ptr[v], n = vn_ptr[v + 1] - s;
    for (int i = 1; i < n; ++i) {
        int key = vn_eids[s + i];
        int j = i - 1;
        while (j >= 0 && vn_eids[s + j] > key) { vn_eids[s + j + 1] = vn_eids[s + j]; --j; }
        vn_eids[s + j + 1] = key;
    }
}

// ---------- per-iteration kernels ----------

// node_sum[v][:] = llrT[v][:] + sum_{e in edges(v)} msg[e][:]
__global__ __launch_bounds__(256) void vn_sum(const float4* __restrict__ llrT,
                                              const float4* __restrict__ msg,
                                              const int* __restrict__ vn_ptr,
                                              const int* __restrict__ vn_eids,
                                              float4* __restrict__ node_sum) {
    int v = blockIdx.x;
    int tid = threadIdx.x;
    float4 acc = llrT[(size_t)v * B4 + tid];
    int s = vn_ptr[v], e = vn_ptr[v + 1];
    #pragma unroll
    for (int k = 0; k < 3; ++k) {
        if (s + k < e) {
            int eid = vn_eids[s + k];
            float4 m = msg[(size_t)eid * B4 + tid];
            acc.x += m.x; acc.y += m.y; acc.z += m.z; acc.w += m.w;
        }
    }
    node_sum[(size_t)v * B4 + tid] = acc;
}

// in-place CN update: t = node_sum[vn_e] - msg[e];  msg[e] = sign_out * phi(psum - p_e)
__global__ __launch_bounds__(256) void cn_update(const float4* __restrict__ node_sum,
                                                 float4* __restrict__ msg,
                                                 const int* __restrict__ cn_ptr,
                                                 const int* __restrict__ vn_con) {
    int j = blockIdx.x;
    int tid = threadIdx.x;
    int s = cn_ptr[j], e = cn_ptr[j + 1];
    int deg = e - s;

    float4 p[6];
    uint4 m = make_uint4(0u, 0u, 0u, 0u);
    float4 psum = make_float4(0.f, 0.f, 0.f, 0.f);

    #pragma unroll
    for (int k = 0; k < 6; ++k) {
        if (k < deg) {
            int eid = s + k;
            int v = vn_con[eid];
            float4 ns = node_sum[(size_t)v * B4 + tid];
            float4 mm = msg[(size_t)eid * B4 + tid];
            float tx = ns.x - mm.x, ty = ns.y - mm.y, tz = ns.z - mm.z, tw = ns.w - mm.w;
            if (tx < 0.f) m.x |= (1u << k);
            if (ty < 0.f) m.y |= (1u << k);
            if (tz < 0.f) m.z |= (1u << k);
            if (tw < 0.f) m.w |= (1u << k);
            float px = phi_f(fabsf(tx));
            float py = phi_f(fabsf(ty));
            float pz = phi_f(fabsf(tz));
            float pw = phi_f(fabsf(tw));
            p[k] = make_float4(px, py, pz, pw);
            psum.x += px; psum.y += py; psum.z += pz; psum.w += pw;
        }
    }

    float ax = (__popc(m.x) & 1) ? -1.f : 1.f;
    float ay = (__popc(m.y) & 1) ? -1.f : 1.f;
    float az = (__popc(m.z) & 1) ? -1.f : 1.f;
    float aw = (__popc(m.w) & 1) ? -1.f : 1.f;

    #pragma unroll
    for (int k = 0; k < 6; ++k) {
        if (k < deg) {
            int eid = s + k;
            float4 o;
            o.x = (((m.x >> k) & 1) ? -ax : ax) * phi_f(psum.x - p[k].x);
            o.y = (((m.y >> k) & 1) ? -ay : ay) * phi_f(psum.y - p[k].y);
            o.z = (((m.z >> k) & 1) ? -az : az) * phi_f(psum.z - p[k].z);
            o.w = (((m.w >> k) & 1) ? -aw : aw) * phi_f(psum.w - p[k].w);
            msg[(size_t)eid * B4 + tid] = o;
        }
    }
}

extern "C" void kernel_launch(void* const* d_in, const int* in_sizes, int n_in,
                              void* d_out, int out_size, void* d_ws, size_t ws_size,
                              hipStream_t stream) {
    const float* llr_ch = (const float*)d_in[0];
    const int* vn_con = (const int*)d_in[1];
    const int* cn_con = (const int*)d_in[2];
    int E = in_sizes[1];
    float* out = (float*)d_out;

    char* ws = (char*)d_ws;
    size_t off = 0;
    auto alloc = [&](size_t bytes) -> void* {
        void* ptr = ws + off;
        off = (off + bytes + 255) & ~(size_t)255;
        return ptr;
    };
    float* llrT     = (float*)alloc((size_t)N_VNS * BATCH * 4);
    float* node_sum = (float*)alloc((size_t)N_VNS * BATCH * 4);
    float* msg      = (float*)alloc((size_t)E * BATCH * 4);
    int* vn_ptr  = (int*)alloc((N_VNS + 1) * 4);
    int* cn_ptr  = (int*)alloc((N_CNS + 1) * 4);
    int* vn_cnt  = (int*)alloc(N_VNS * 4);
    int* cn_cnt  = (int*)alloc(N_CNS * 4);
    int* vn_fill = (int*)alloc(N_VNS * 4);
    int* vn_eids = (int*)alloc((size_t)E * 4);

    hipMemsetAsync(vn_cnt, 0, N_VNS * 4, stream);
    hipMemsetAsync(cn_cnt, 0, N_CNS * 4, stream);
    hipMemsetAsync(vn_fill, 0, N_VNS * 4, stream);
    hipMemsetAsync(msg, 0, (size_t)E * BATCH * 4, stream);

    // llrT[v][b] = -llr_ch[b][v]
    transpose_neg<<<dim3(N_VNS / 32, BATCH / 32), dim3(32, 8), 0, stream>>>(
        llr_ch, llrT, BATCH, N_VNS);

    count_edges<<<(E + 255) / 256, 256, 0, stream>>>(vn_con, cn_con, E, vn_cnt, cn_cnt);
    scan_excl<<<1, 1024, 0, stream>>>(vn_cnt, N_VNS, vn_ptr);
    scan_excl<<<1, 1024, 0, stream>>>(cn_cnt, N_CNS, cn_ptr);
    fill_vn<<<(E + 255) / 256, 256, 0, stream>>>(vn_con, E, vn_ptr, vn_fill, vn_eids);
    sort_vn<<<(N_VNS + 255) / 256, 256, 0, stream>>>(vn_ptr, vn_eids);

    for (int it = 0; it < NUM_ITER; ++it) {
        vn_sum<<<N_VNS, 256, 0, stream>>>((const float4*)llrT, (const float4*)msg,
                                          vn_ptr, vn_eids, (float4*)node_sum);
        cn_update<<<N_CNS, 256, 0, stream>>>((const float4*)node_sum, (float4*)msg,
                                             cn_ptr, vn_con);
    }

    // x_tot = llrT + segment_sum(msg); out[b][v] = -x_tot[v][b]
    vn_sum<<<N_VNS, 256, 0, stream>>>((const float4*)llrT, (const float4*)msg,
                                      vn_ptr, vn_eids, (float4*)node_sum);
    transpose_neg<<<dim3(BATCH / 32, N_VNS / 32), dim3(32, 8), 0, stream>>>(
        node_sum, out, N_VNS, BATCH);
}

// Round 3
// 792.881 us; speedup vs baseline: 2.3381x; 1.8865x over previous
//
#include <hip/hip_runtime.h>

#define N_VNS   8192
#define N_CNS   4096
#define BATCH   1024
#define NUM_ITER 20
#define MAX_E   24576
#define PHI_MIN 8.5e-08f
#define PHI_MAX 16.635532f
#define LDS_BYTES ((MAX_E + N_CNS) * 4)

// phi(x) = log((e^x+1)/(e^x-1)) via hardware exp2/log2/rcp.
// e-1 clamped to 2^-23 (1 ulp at 1.0) to mimic the reference's f32 rounding
// at the PHI_MIN boundary and avoid rcp(0)=inf.
__device__ __forceinline__ float phi_f(float x) {
    x = fminf(fmaxf(x, PHI_MIN), PHI_MAX);
    float e = __builtin_amdgcn_exp2f(x * 1.44269504088896f);
    float em1 = fmaxf(e - 1.0f, 1.1920929e-07f);
    float r = (e + 1.0f) * __builtin_amdgcn_rcpf(em1);
    return __builtin_amdgcn_logf(r) * 0.693147180559945f;
}

// ---------- setup kernels (run once per launch, ~30 us total) ----------

__global__ void count_edges(const int* __restrict__ vn_con, const int* __restrict__ cn_con,
                            int E, int* __restrict__ vn_cnt, int* __restrict__ cn_cnt) {
    int e = blockIdx.x * 256 + threadIdx.x;
    if (e < E) {
        atomicAdd(&vn_cnt[vn_con[e]], 1);
        atomicAdd(&cn_cnt[cn_con[e]], 1);
    }
}

__global__ void scan_excl(const int* __restrict__ cnt, int n, int* __restrict__ ptr) {
    __shared__ int sh[1024];
    int carry = 0;
    if (threadIdx.x == 0) ptr[0] = 0;
    for (int base = 0; base < n; base += 1024) {
        int i = base + (int)threadIdx.x;
        int v = (i < n) ? cnt[i] : 0;
        sh[threadIdx.x] = v;
        __syncthreads();
        for (int off = 1; off < 1024; off <<= 1) {
            int add = ((int)threadIdx.x >= off) ? sh[threadIdx.x - off] : 0;
            __syncthreads();
            sh[threadIdx.x] += add;
            __syncthreads();
        }
        if (i < n) ptr[i + 1] = carry + sh[threadIdx.x];
        carry += sh[1023];
        __syncthreads();
    }
}

__global__ void fill_vn(const int* __restrict__ vn_con, int E,
                        const int* __restrict__ vn_ptr, int* __restrict__ vn_fill,
                        int* __restrict__ vn_eids) {
    int e = blockIdx.x * 256 + threadIdx.x;
    if (e < E) {
        int v = vn_con[e];
        int slot = atomicAdd(&vn_fill[v], 1);
        vn_eids[vn_ptr[v] + slot] = e;
    }
}

// deterministic CSR: sort each vn's (<=3) edge ids ascending, then pack
// vn_pack[v][k] = eid | (cn << 15), 0xFFFFFFFF sentinel beyond degree.
__global__ void sort_pack_vn(const int* __restrict__ vn_ptr, int* __restrict__ vn_eids,
                             const int* __restrict__ cn_con, unsigned* __restrict__ vn_pack) {
    int v = blockIdx.x * 256 + threadIdx.x;
    if (v >= N_VNS) return;
    int s = vn_ptr[v], n = vn_ptr[v + 1] - s;
    for (int i = 1; i < n; ++i) {
        int key = vn_eids[s + i];
        int j = i - 1;
        while (j >= 0 && vn_eids[s + j] > key) { vn_eids[s + j + 1] = vn_eids[s + j]; --j; }
        vn_eids[s + j + 1] = key;
    }
    for (int k = 0; k < 3; ++k) {
        unsigned p = 0xFFFFFFFFu;
        if (k < n) {
            int eid = vn_eids[s + k];
            p = (unsigned)eid | ((unsigned)cn_con[eid] << 15);
        }
        vn_pack[v * 3 + k] = p;
    }
}

// ---------- the whole decode: one block per batch element ----------
// LDS: t[MAX_E]   = VN->CN messages for this batch element
//      psum[N_CNS] = sum_e phi(|t_e|), with CN sign-parity in the sign bit
// Thread tid owns VNs {tid + 1024*i, i<8} and CNs {tid + 1024*i, i<4}.
// msg reconstruction: msg_e = parity * sgn(t_e) * phi(|psum| - phi(|t_e|))
// -- arithmetic identical (same op order) to the unfused reference kernels.

__global__ __launch_bounds__(1024, 4) void decode(const float* __restrict__ llr_ch,
                                                  float* __restrict__ out,
                                                  const unsigned* __restrict__ vn_pack,
                                                  const int* __restrict__ cn_ptr) {
    extern __shared__ float lds[];
    float* t = lds;                 // [MAX_E]
    float* psum = lds + MAX_E;      // [N_CNS]

    int b = blockIdx.x, tid = threadIdx.x;
    const float* llr_row = llr_ch + (size_t)b * N_VNS;

    float llr[8];
    unsigned pk[8][3];
    #pragma unroll
    for (int i = 0; i < 8; ++i) {
        int v = i * 1024 + tid;
        llr[i] = -llr_row[v];
        #pragma unroll
        for (int k = 0; k < 3; ++k) pk[i][k] = vn_pack[v * 3 + k];
    }
    int cs[4], cd[4];
    #pragma unroll
    for (int i = 0; i < 4; ++i) {
        int c = i * 1024 + tid;
        cs[i] = cn_ptr[c];
        cd[i] = cn_ptr[c + 1] - cs[i];
    }

    // iteration 1's vn_update with msg=0: t_e = llr[vn_e]
    #pragma unroll
    for (int i = 0; i < 8; ++i)
        #pragma unroll
        for (int k = 0; k < 3; ++k)
            if (pk[i][k] != 0xFFFFFFFFu) t[pk[i][k] & 0x7FFFu] = llr[i];
    __syncthreads();

    for (int it = 0; it < NUM_ITER; ++it) {
        // ---- CN phase: psum[c] = +/- sum_k phi(|t|), sign bit = parity ----
        #pragma unroll
        for (int i = 0; i < 4; ++i) {
            int s = cs[i], d = cd[i];
            float ps = 0.f;
            unsigned par = 0u;
            #pragma unroll
            for (int k = 0; k < 6; ++k) {
                if (k < d) {
                    float tv = t[s + k];
                    if (tv < 0.f) par ^= 1u;
                    ps += phi_f(fabsf(tv));
                }
            }
            psum[i * 1024 + tid] = par ? -ps : ps;
        }
        __syncthreads();
        if (it == NUM_ITER - 1) break;

        // ---- VN phase: reconstruct msgs, new t_e = node_sum - msg_e ----
        #pragma unroll
        for (int i = 0; i < 8; ++i) {
            float ns = llr[i];
            float msg[3];
            #pragma unroll
            for (int k = 0; k < 3; ++k) {
                msg[k] = 0.f;
                unsigned p = pk[i][k];
                if (p != 0xFFFFFFFFu) {
                    float tv = t[p & 0x7FFFu];
                    float ps = psum[p >> 15];
                    bool neg = (tv < 0.f) ^ (ps < 0.f);
                    float m = phi_f(fabsf(ps) - phi_f(fabsf(tv)));
                    m = neg ? -m : m;
                    msg[k] = m;
                    ns += m;
                }
            }
            #pragma unroll
            for (int k = 0; k < 3; ++k) {
                unsigned p = pk[i][k];
                if (p != 0xFFFFFFFFu) t[p & 0x7FFFu] = ns - msg[k];
            }
        }
        __syncthreads();
    }

    // ---- marginalization: out[b][v] = -(llr + sum_e msg_e) ----
    float* orow = out + (size_t)b * N_VNS;
    #pragma unroll
    for (int i = 0; i < 8; ++i) {
        float ns = llr[i];
        #pragma unroll
        for (int k = 0; k < 3; ++k) {
            unsigned p = pk[i][k];
            if (p != 0xFFFFFFFFu) {
                float tv = t[p & 0x7FFFu];
                float ps = psum[p >> 15];
                bool neg = (tv < 0.f) ^ (ps < 0.f);
                float m = phi_f(fabsf(ps) - phi_f(fabsf(tv)));
                ns += neg ? -m : m;
            }
        }
        orow[i * 1024 + tid] = -ns;
    }
}

extern "C" void kernel_launch(void* const* d_in, const int* in_sizes, int n_in,
                              void* d_out, int out_size, void* d_ws, size_t ws_size,
                              hipStream_t stream) {
    const float* llr_ch = (const float*)d_in[0];
    const int* vn_con = (const int*)d_in[1];
    const int* cn_con = (const int*)d_in[2];
    int E = in_sizes[1];
    float* out = (float*)d_out;

    char* ws = (char*)d_ws;
    size_t off = 0;
    auto alloc = [&](size_t bytes) -> void* {
        void* ptr = ws + off;
        off = (off + bytes + 255) & ~(size_t)255;
        return ptr;
    };
    int* vn_ptr  = (int*)alloc((N_VNS + 1) * 4);
    int* cn_ptr  = (int*)alloc((N_CNS + 1) * 4);
    int* vn_cnt  = (int*)alloc(N_VNS * 4);
    int* cn_cnt  = (int*)alloc(N_CNS * 4);
    int* vn_fill = (int*)alloc(N_VNS * 4);
    int* vn_eids = (int*)alloc((size_t)E * 4);
    unsigned* vn_pack = (unsigned*)alloc((size_t)N_VNS * 3 * 4);

    hipMemsetAsync(vn_cnt, 0, N_VNS * 4, stream);
    hipMemsetAsync(cn_cnt, 0, N_CNS * 4, stream);
    hipMemsetAsync(vn_fill, 0, N_VNS * 4, stream);

    count_edges<<<(E + 255) / 256, 256, 0, stream>>>(vn_con, cn_con, E, vn_cnt, cn_cnt);
    scan_excl<<<1, 1024, 0, stream>>>(vn_cnt, N_VNS, vn_ptr);
    scan_excl<<<1, 1024, 0, stream>>>(cn_cnt, N_CNS, cn_ptr);
    fill_vn<<<(E + 255) / 256, 256, 0, stream>>>(vn_con, E, vn_ptr, vn_fill, vn_eids);
    sort_pack_vn<<<(N_VNS + 255) / 256, 256, 0, stream>>>(vn_ptr, vn_eids, cn_con, vn_pack);

    static bool attr_set = false;
    if (!attr_set) {
        hipFuncSetAttribute((const void*)decode,
                            hipFuncAttributeMaxDynamicSharedMemorySize, LDS_BYTES);
        attr_set = true;
    }
    decode<<<BATCH, 1024, LDS_BYTES, stream>>>(llr_ch, out, vn_pack, cn_ptr);
}

// Round 4
// 603.198 us; speedup vs baseline: 3.0733x; 1.3145x over previous
//
#include <hip/hip_runtime.h>

#define N_VNS   8192
#define N_CNS   4096
#define BATCH   1024
#define NUM_ITER 20
#define MAX_E   24576
#define PHI_MIN 8.5e-08f
#define PHI_MAX 16.635532f
// q padded: one extra slot every 32 (bank-conflict swizzle)
#define QSLOTS  (MAX_E + MAX_E / 32)
#define LDS_BYTES ((QSLOTS + N_CNS) * 4)

// phi(x) = log((e^x+1)/(e^x-1)) via hardware exp2/log2/rcp.
// e-1 clamped to 2^-23 (1 ulp at 1.0) to mimic the reference's f32 rounding
// at the PHI_MIN boundary and avoid rcp(0)=inf.
__device__ __forceinline__ float phi_f(float x) {
    x = fminf(fmaxf(x, PHI_MIN), PHI_MAX);
    float e = __builtin_amdgcn_exp2f(x * 1.44269504088896f);
    float em1 = fmaxf(e - 1.0f, 1.1920929e-07f);
    float r = (e + 1.0f) * __builtin_amdgcn_rcpf(em1);
    return __builtin_amdgcn_logf(r) * 0.693147180559945f;
}

__device__ __forceinline__ unsigned swz(unsigned e) { return e + (e >> 5); }

// ---------- setup kernels (run once per launch, ~10 us total) ----------

__global__ void count_edges(const int* __restrict__ vn_con, const int* __restrict__ cn_con,
                            int E, int* __restrict__ vn_cnt, int* __restrict__ cn_cnt) {
    int e = blockIdx.x * 256 + threadIdx.x;
    if (e < E) {
        atomicAdd(&vn_cnt[vn_con[e]], 1);
        atomicAdd(&cn_cnt[cn_con[e]], 1);
    }
}

__global__ void scan_excl(const int* __restrict__ cnt, int n, int* __restrict__ ptr) {
    __shared__ int sh[1024];
    int carry = 0;
    if (threadIdx.x == 0) ptr[0] = 0;
    for (int base = 0; base < n; base += 1024) {
        int i = base + (int)threadIdx.x;
        int v = (i < n) ? cnt[i] : 0;
        sh[threadIdx.x] = v;
        __syncthreads();
        for (int off = 1; off < 1024; off <<= 1) {
            int add = ((int)threadIdx.x >= off) ? sh[threadIdx.x - off] : 0;
            __syncthreads();
            sh[threadIdx.x] += add;
            __syncthreads();
        }
        if (i < n) ptr[i + 1] = carry + sh[threadIdx.x];
        carry += sh[1023];
        __syncthreads();
    }
}

__global__ void fill_vn(const int* __restrict__ vn_con, int E,
                        const int* __restrict__ vn_ptr, int* __restrict__ vn_fill,
                        int* __restrict__ vn_eids) {
    int e = blockIdx.x * 256 + threadIdx.x;
    if (e < E) {
        int v = vn_con[e];
        int slot = atomicAdd(&vn_fill[v], 1);
        vn_eids[vn_ptr[v] + slot] = e;
    }
}

// deterministic CSR: sort each vn's (<=3) edge ids ascending, then pack
// vn_pack[v][k] = swizzled_eid | (cn << 15); 0xFFFFFFFF sentinel beyond degree.
__global__ void sort_pack_vn(const int* __restrict__ vn_ptr, int* __restrict__ vn_eids,
                             const int* __restrict__ cn_con, unsigned* __restrict__ vn_pack) {
    int v = blockIdx.x * 256 + threadIdx.x;
    if (v >= N_VNS) return;
    int s = vn_ptr[v], n = vn_ptr[v + 1] - s;
    for (int i = 1; i < n; ++i) {
        int key = vn_eids[s + i];
        int j = i - 1;
        while (j >= 0 && vn_eids[s + j] > key) { vn_eids[s + j + 1] = vn_eids[s + j]; --j; }
        vn_eids[s + j + 1] = key;
    }
    for (int k = 0; k < 3; ++k) {
        unsigned p = 0xFFFFFFFFu;
        if (k < n) {
            int eid = vn_eids[s + k];
            p = swz((unsigned)eid) | ((unsigned)cn_con[eid] << 15);
        }
        vn_pack[v * 3 + k] = p;
    }
}

// ---------- the whole decode: one block per batch element ----------
// LDS: q[QSLOTS]   : q_e = sgn(t_e)*phi(|t_e|), phi-domain VN->CN messages,
//                    stored at swizzled index e + e/32 (bank-conflict pad)
//      psum[N_CNS] : sum_e phi(|t_e|), CN sign-parity encoded in bit 31
// CN phase is pure LDS+adds (no transcendentals); VN phase does the minimum
// 2 phi per edge. All values bit-identical to the unfused formulation.

__global__ __launch_bounds__(1024, 4) void decode(const float* __restrict__ llr_ch,
                                                  float* __restrict__ out,
                                                  const unsigned* __restrict__ vn_pack,
                                                  const int* __restrict__ cn_ptr) {
    extern __shared__ unsigned lds[];
    unsigned* q = lds;                  // [QSLOTS]
    unsigned* psum = lds + QSLOTS;      // [N_CNS]

    int b = blockIdx.x, tid = threadIdx.x;
    const float* llr_row = llr_ch + (size_t)b * N_VNS;

    float llr[8];
    unsigned pk[8][3];
    #pragma unroll
    for (int i = 0; i < 8; ++i) {
        int v = i * 1024 + tid;
        llr[i] = -llr_row[v];
        #pragma unroll
        for (int k = 0; k < 3; ++k) pk[i][k] = vn_pack[v * 3 + k];
    }
    int cs[4], cd[4];
    #pragma unroll
    for (int i = 0; i < 4; ++i) {
        int c = i * 1024 + tid;
        cs[i] = cn_ptr[c];
        cd[i] = cn_ptr[c + 1] - cs[i];
    }

    // iteration 1's vn_update with msg=0: t_e = llr[vn_e] -> phi domain
    #pragma unroll
    for (int i = 0; i < 8; ++i) {
        unsigned nq = __float_as_uint(phi_f(fabsf(llr[i]))) |
                      (__float_as_uint(llr[i]) & 0x80000000u);
        #pragma unroll
        for (int k = 0; k < 3; ++k)
            if (pk[i][k] != 0xFFFFFFFFu) q[pk[i][k] & 0x7FFFu] = nq;
    }
    __syncthreads();

    for (int it = 0; it < NUM_ITER; ++it) {
        // ---- CN phase: psum[c] = (+/-) sum_k |q_k|, parity in bit 31 ----
        #pragma unroll
        for (int i = 0; i < 4; ++i) {
            int s = cs[i], d = cd[i];
            float ps = 0.f;
            unsigned par = 0u;
            #pragma unroll
            for (int k = 0; k < 6; ++k) {
                if (k < d) {
                    unsigned qb = q[swz((unsigned)(s + k))];
                    par ^= qb;
                    ps += __uint_as_float(qb & 0x7FFFFFFFu);
                }
            }
            psum[i * 1024 + tid] = __float_as_uint(ps) | (par & 0x80000000u);
        }
        __syncthreads();
        if (it == NUM_ITER - 1) break;

        // ---- VN phase: msg_e = sgn*phi(|ps|-|q_e|); new q = phi(ns - msg) ----
        #pragma unroll
        for (int i = 0; i < 8; ++i) {
            float ns = llr[i];
            float msg[3];
            #pragma unroll
            for (int k = 0; k < 3; ++k) {
                msg[k] = 0.f;
                unsigned p = pk[i][k];
                if (p != 0xFFFFFFFFu) {
                    unsigned qb = q[p & 0x7FFFu];
                    unsigned pb = psum[p >> 15];
                    float a = __uint_as_float(pb & 0x7FFFFFFFu) -
                              __uint_as_float(qb & 0x7FFFFFFFu);
                    float m = __uint_as_float(__float_as_uint(phi_f(a)) ^
                                              ((qb ^ pb) & 0x80000000u));
                    msg[k] = m;
                    ns += m;
                }
            }
            #pragma unroll
            for (int k = 0; k < 3; ++k) {
                unsigned p = pk[i][k];
                if (p != 0xFFFFFFFFu) {
                    float tnew = ns - msg[k];
                    unsigned nq = __float_as_uint(phi_f(fabsf(tnew))) |
                                  (__float_as_uint(tnew) & 0x80000000u);
                    q[p & 0x7FFFu] = nq;
                }
            }
        }
        __syncthreads();
    }

    // ---- marginalization: out[b][v] = -(llr + sum_e msg_e) ----
    float* orow = out + (size_t)b * N_VNS;
    #pragma unroll
    for (int i = 0; i < 8; ++i) {
        float ns = llr[i];
        #pragma unroll
        for (int k = 0; k < 3; ++k) {
            unsigned p = pk[i][k];
            if (p != 0xFFFFFFFFu) {
                unsigned qb = q[p & 0x7FFFu];
                unsigned pb = psum[p >> 15];
                float a = __uint_as_float(pb & 0x7FFFFFFFu) -
                          __uint_as_float(qb & 0x7FFFFFFFu);
                ns += __uint_as_float(__float_as_uint(phi_f(a)) ^
                                      ((qb ^ pb) & 0x80000000u));
            }
        }
        orow[i * 1024 + tid] = -ns;
    }
}

extern "C" void kernel_launch(void* const* d_in, const int* in_sizes, int n_in,
                              void* d_out, int out_size, void* d_ws, size_t ws_size,
                              hipStream_t stream) {
    const float* llr_ch = (const float*)d_in[0];
    const int* vn_con = (const int*)d_in[1];
    const int* cn_con = (const int*)d_in[2];
    int E = in_sizes[1];
    float* out = (float*)d_out;

    char* ws = (char*)d_ws;
    size_t off = 0;
    auto alloc = [&](size_t bytes) -> void* {
        void* ptr = ws + off;
        off = (off + bytes + 255) & ~(size_t)255;
        return ptr;
    };
    int* vn_ptr  = (int*)alloc((N_VNS + 1) * 4);
    int* cn_ptr  = (int*)alloc((N_CNS + 1) * 4);
    int* vn_cnt  = (int*)alloc(N_VNS * 4);
    int* cn_cnt  = (int*)alloc(N_CNS * 4);
    int* vn_fill = (int*)alloc(N_VNS * 4);
    int* vn_eids = (int*)alloc((size_t)E * 4);
    unsigned* vn_pack = (unsigned*)alloc((size_t)N_VNS * 3 * 4);

    hipMemsetAsync(vn_cnt, 0, N_VNS * 4, stream);
    hipMemsetAsync(cn_cnt, 0, N_CNS * 4, stream);
    hipMemsetAsync(vn_fill, 0, N_VNS * 4, stream);

    count_edges<<<(E + 255) / 256, 256, 0, stream>>>(vn_con, cn_con, E, vn_cnt, cn_cnt);
    scan_excl<<<1, 1024, 0, stream>>>(vn_cnt, N_VNS, vn_ptr);
    scan_excl<<<1, 1024, 0, stream>>>(cn_cnt, N_CNS, cn_ptr);
    fill_vn<<<(E + 255) / 256, 256, 0, stream>>>(vn_con, E, vn_ptr, vn_fill, vn_eids);
    sort_pack_vn<<<(N_VNS + 255) / 256, 256, 0, stream>>>(vn_ptr, vn_eids, cn_con, vn_pack);

    static bool attr_set = false;
    if (!attr_set) {
        hipFuncSetAttribute((const void*)decode,
                            hipFuncAttributeMaxDynamicSharedMemorySize, LDS_BYTES);
        attr_set = true;
    }
    decode<<<BATCH, 1024, LDS_BYTES, stream>>>(llr_ch, out, vn_pack, cn_ptr);
}

// Round 5
// 560.386 us; speedup vs baseline: 3.3081x; 1.0764x over previous
//
#include <hip/hip_runtime.h>

#define N_VNS   8192
#define N_CNS   4096
#define BATCH   1024
#define NUM_ITER 20
#define MAX_E   24576           // == 6 * N_CNS, fixed 6-slot-per-CN layout
#define PHI_MIN 8.5e-08f
#define PHI_MAX 16.635532f
#define LOG2E   1.44269504088896f
#define LN2     0.693147180559945f
// scaled-domain clip bounds: [PHI_MIN*log2e, PHI_MAX*log2e]
#define YMIN2   1.2263e-07f
#define YMAX2   24.0f
#define LDS_BYTES ((MAX_E + N_CNS) * 4)

// Scaled phi: g(y) = log2((2^y+1)/(2^y-1)).  Whole decoder runs in the
// log2-scaled domain (all messages/sums are linear in scale), so the
// x*log2e / *ln2 multiplies amortize to one scale at entry + one at exit.
// e-1 clamped to 2^-23 to mimic reference f32 rounding at the PHI_MIN edge.
__device__ __forceinline__ float phi2_f(float y) {
    y = fminf(fmaxf(y, YMIN2), YMAX2);              // v_med3_f32
    float e = __builtin_amdgcn_exp2f(y);
    float em1 = fmaxf(e - 1.0f, 1.1920929e-07f);
    return __builtin_amdgcn_logf((e + 1.0f) * __builtin_amdgcn_rcpf(em1));
}

// ---------- setup kernels (run once per launch, ~10 us total) ----------

__global__ void count_edges(const int* __restrict__ vn_con, const int* __restrict__ cn_con,
                            int E, int* __restrict__ vn_cnt, int* __restrict__ cn_cnt) {
    int e = blockIdx.x * 256 + threadIdx.x;
    if (e < E) {
        atomicAdd(&vn_cnt[vn_con[e]], 1);
        atomicAdd(&cn_cnt[cn_con[e]], 1);
    }
}

__global__ void scan_excl(const int* __restrict__ cnt, int n, int* __restrict__ ptr) {
    __shared__ int sh[1024];
    int carry = 0;
    if (threadIdx.x == 0) ptr[0] = 0;
    for (int base = 0; base < n; base += 1024) {
        int i = base + (int)threadIdx.x;
        int v = (i < n) ? cnt[i] : 0;
        sh[threadIdx.x] = v;
        __syncthreads();
        for (int off = 1; off < 1024; off <<= 1) {
            int add = ((int)threadIdx.x >= off) ? sh[threadIdx.x - off] : 0;
            __syncthreads();
            sh[threadIdx.x] += add;
            __syncthreads();
        }
        if (i < n) ptr[i + 1] = carry + sh[threadIdx.x];
        carry += sh[1023];
        __syncthreads();
    }
}

__global__ void fill_vn(const int* __restrict__ vn_con, int E,
                        const int* __restrict__ vn_ptr, int* __restrict__ vn_fill,
                        int* __restrict__ vn_eids) {
    int e = blockIdx.x * 256 + threadIdx.x;
    if (e < E) {
        int v = vn_con[e];
        int slot = atomicAdd(&vn_fill[v], 1);
        vn_eids[vn_ptr[v] + slot] = e;
    }
}

// deterministic CSR: sort each vn's (<=3) edge ids ascending, then pack
// vn_pack[v][k] = qslot | (cn << 15); qslot = 6*cn + (eid - cn_ptr[cn])
// (edge's rank within its CN -- edges are sorted by cn so this is dense,
// pad slots 6*cn+deg..6*cn+5 stay zero). 0xFFFFFFFF sentinel beyond degree.
__global__ void sort_pack_vn(const int* __restrict__ vn_ptr, int* __restrict__ vn_eids,
                             const int* __restrict__ cn_con, const int* __restrict__ cn_ptr,
                             unsigned* __restrict__ vn_pack) {
    int v = blockIdx.x * 256 + threadIdx.x;
    if (v >= N_VNS) return;
    int s = vn_ptr[v], n = vn_ptr[v + 1] - s;
    for (int i = 1; i < n; ++i) {
        int key = vn_eids[s + i];
        int j = i - 1;
        while (j >= 0 && vn_eids[s + j] > key) { vn_eids[s + j + 1] = vn_eids[s + j]; --j; }
        vn_eids[s + j + 1] = key;
    }
    for (int k = 0; k < 3; ++k) {
        unsigned p = 0xFFFFFFFFu;
        if (k < n) {
            int eid = vn_eids[s + k];
            int cn = cn_con[eid];
            unsigned slot = 6u * cn + (unsigned)(eid - cn_ptr[cn]);
            p = slot | ((unsigned)cn << 15);
        }
        vn_pack[v * 3 + k] = p;
    }
}

// ---------- the whole decode: one block per batch element ----------
// LDS: q[MAX_E]    : q_e = sgn(t_e)*phi2(|t_e|), phi-domain VN->CN messages,
//                    fixed 6 slots per CN (pad slots +0.0f forever)
//      psum[N_CNS] : sum_e phi2(|t_e|), CN sign-parity encoded in bit 31
// CN phase: branchless, 3x ds_read_b64 + adds/xors per CN, no transcendentals.
// VN phase: the algorithmic minimum 2 phi per edge.

__global__ __launch_bounds__(1024, 4) void decode(const float* __restrict__ llr_ch,
                                                  float* __restrict__ out,
                                                  const unsigned* __restrict__ vn_pack) {
    extern __shared__ unsigned lds[];
    unsigned* q = lds;                  // [MAX_E]
    unsigned* psum = lds + MAX_E;       // [N_CNS]

    int b = blockIdx.x, tid = threadIdx.x;
    const float* llr_row = llr_ch + (size_t)b * N_VNS;

    float llr[8];
    unsigned pk[8][3];
    #pragma unroll
    for (int i = 0; i < 8; ++i) {
        int v = i * 1024 + tid;
        llr[i] = -llr_row[v] * LOG2E;   // enter scaled domain
        #pragma unroll
        for (int k = 0; k < 3; ++k) pk[i][k] = vn_pack[v * 3 + k];
    }

    // zero all q slots (pads must be +0.0), then initial store t_e = llr[vn_e]
    #pragma unroll
    for (int k = 0; k < 24; ++k) q[k * 1024 + tid] = 0u;
    __syncthreads();
    #pragma unroll
    for (int i = 0; i < 8; ++i) {
        unsigned nq = __float_as_uint(phi2_f(fabsf(llr[i]))) |
                      (__float_as_uint(llr[i]) & 0x80000000u);
        #pragma unroll
        for (int k = 0; k < 3; ++k)
            if (pk[i][k] != 0xFFFFFFFFu) q[pk[i][k] & 0x7FFFu] = nq;
    }
    __syncthreads();

    for (int it = 0; it < NUM_ITER; ++it) {
        // ---- CN phase: psum[c] = (+/-) sum_k |q_k|, parity in bit 31 ----
        #pragma unroll
        for (int i = 0; i < 4; ++i) {
            int c = i * 1024 + tid;
            const uint2* qp = reinterpret_cast<const uint2*>(q + 6 * c);
            uint2 q01 = qp[0], q23 = qp[1], q45 = qp[2];
            unsigned par = q01.x ^ q01.y ^ q23.x ^ q23.y ^ q45.x ^ q45.y;
            float ps = __uint_as_float(q01.x & 0x7FFFFFFFu);
            ps += __uint_as_float(q01.y & 0x7FFFFFFFu);
            ps += __uint_as_float(q23.x & 0x7FFFFFFFu);
            ps += __uint_as_float(q23.y & 0x7FFFFFFFu);
            ps += __uint_as_float(q45.x & 0x7FFFFFFFu);
            ps += __uint_as_float(q45.y & 0x7FFFFFFFu);
            psum[c] = __float_as_uint(ps) | (par & 0x80000000u);
        }
        __syncthreads();
        if (it == NUM_ITER - 1) break;

        // ---- VN phase: msg_e = sgn*phi2(|ps|-|q_e|); new q = phi2(ns - msg) ----
        #pragma unroll
        for (int i = 0; i < 8; ++i) {
            float ns = llr[i];
            float msg[3];
            #pragma unroll
            for (int k = 0; k < 3; ++k) {
                msg[k] = 0.f;
                unsigned p = pk[i][k];
                if (p != 0xFFFFFFFFu) {
                    unsigned qb = q[p & 0x7FFFu];
                    unsigned pb = psum[p >> 15];
                    float a = __uint_as_float(pb & 0x7FFFFFFFu) -
                              __uint_as_float(qb & 0x7FFFFFFFu);
                    float m = __uint_as_float(__float_as_uint(phi2_f(a)) ^
                                              ((qb ^ pb) & 0x80000000u));
                    msg[k] = m;
                    ns += m;
                }
            }
            #pragma unroll
            for (int k = 0; k < 3; ++k) {
                unsigned p = pk[i][k];
                if (p != 0xFFFFFFFFu) {
                    float tnew = ns - msg[k];
                    unsigned nq = __float_as_uint(phi2_f(fabsf(tnew))) |
                                  (__float_as_uint(tnew) & 0x80000000u);
                    q[p & 0x7FFFu] = nq;
                }
            }
        }
        __syncthreads();
    }

    // ---- marginalization: out[b][v] = -(llr + sum_e msg_e) / log2e ----
    float* orow = out + (size_t)b * N_VNS;
    #pragma unroll
    for (int i = 0; i < 8; ++i) {
        float ns = llr[i];
        #pragma unroll
        for (int k = 0; k < 3; ++k) {
            unsigned p = pk[i][k];
            if (p != 0xFFFFFFFFu) {
                unsigned qb = q[p & 0x7FFFu];
                unsigned pb = psum[p >> 15];
                float a = __uint_as_float(pb & 0x7FFFFFFFu) -
                          __uint_as_float(qb & 0x7FFFFFFFu);
                ns += __uint_as_float(__float_as_uint(phi2_f(a)) ^
                                      ((qb ^ pb) & 0x80000000u));
            }
        }
        orow[i * 1024 + tid] = -ns * LN2;   // leave scaled domain
    }
}

extern "C" void kernel_launch(void* const* d_in, const int* in_sizes, int n_in,
                              void* d_out, int out_size, void* d_ws, size_t ws_size,
                              hipStream_t stream) {
    const float* llr_ch = (const float*)d_in[0];
    const int* vn_con = (const int*)d_in[1];
    const int* cn_con = (const int*)d_in[2];
    int E = in_sizes[1];
    float* out = (float*)d_out;

    char* ws = (char*)d_ws;
    size_t off = 0;
    auto alloc = [&](size_t bytes) -> void* {
        void* ptr = ws + off;
        off = (off + bytes + 255) & ~(size_t)255;
        return ptr;
    };
    int* vn_ptr  = (int*)alloc((N_VNS + 1) * 4);
    int* cn_ptr  = (int*)alloc((N_CNS + 1) * 4);
    int* vn_cnt  = (int*)alloc(N_VNS * 4);
    int* cn_cnt  = (int*)alloc(N_CNS * 4);
    int* vn_fill = (int*)alloc(N_VNS * 4);
    int* vn_eids = (int*)alloc((size_t)E * 4);
    unsigned* vn_pack = (unsigned*)alloc((size_t)N_VNS * 3 * 4);

    hipMemsetAsync(vn_cnt, 0, N_VNS * 4, stream);
    hipMemsetAsync(cn_cnt, 0, N_CNS * 4, stream);
    hipMemsetAsync(vn_fill, 0, N_VNS * 4, stream);

    count_edges<<<(E + 255) / 256, 256, 0, stream>>>(vn_con, cn_con, E, vn_cnt, cn_cnt);
    scan_excl<<<1, 1024, 0, stream>>>(vn_cnt, N_VNS, vn_ptr);
    scan_excl<<<1, 1024, 0, stream>>>(cn_cnt, N_CNS, cn_ptr);
    fill_vn<<<(E + 255) / 256, 256, 0, stream>>>(vn_con, E, vn_ptr, vn_fill, vn_eids);
    sort_pack_vn<<<(N_VNS + 255) / 256, 256, 0, stream>>>(vn_ptr, vn_eids, cn_con, cn_ptr,
                                                          vn_pack);

    static bool attr_set = false;
    if (!attr_set) {
        hipFuncSetAttribute((const void*)decode,
                            hipFuncAttributeMaxDynamicSharedMemorySize, LDS_BYTES);
        attr_set = true;
    }
    decode<<<BATCH, 1024, LDS_BYTES, stream>>>(llr_ch, out, vn_pack);
}